// Round 16
// baseline (246.878 us; speedup 1.0000x reference)
//
#include <hip/hip_runtime.h>
#include <hip/hip_bf16.h>

#define BB 16
#define NN 64
#define PREVN 6
#define PREDN 30
#define HH 256
#define EE 4032              // NN*(NN-1)
#define EROWS (BB*EE)        // 64512
#define NROWS (BB*NN)        // 1024

typedef short short8 __attribute__((ext_vector_type(8)));
typedef float f32x4 __attribute__((ext_vector_type(4)));

// ---- f32 workspace layout (float element offsets) ----
enum : int {
  OFF_STATS_E = 0,       // 1024: [0:256]=sum [256:512]=sumsq
  OFF_STATS_M = 1024,    // 1024
  OFF_XRS     = 2048,    // 262144 f32 slots = 524288 bf16: XR ++ XS
  F32_END     = 264192
};
// ---- bf16 area (element offsets within wb = (bf16*)(ws + F32_END)) ----
enum : size_t {
  BO_W1TE  = 0,          // 256*512 (n2e W1^T)
  BO_W2TE  = 131072,     // 256*256
  BO_W1TN  = 196608,     // 256*512 (e2n W1^T)
  BO_W2TN  = 327680,     // 256*256
  BO_WFT   = 393216,     // 256*512 (W_fuse^T)
  BO_WPT   = 524288,     // 64*256  (W_pred^T, zero-padded cols 60..63)
  BO_XG    = 540672,     // 1024*256 raw x (bf16)
  BO_NODES = 802816,     // 1024*512
  BO_M2    = 1327104,    // 1024*256
  BO_FG    = 1589248,    // 1024*256 fused
  BO_E2    = 1851392     // 64512*256
};

// fast ELU: exp(x)-1 via v_exp_f32
__device__ __forceinline__ float eluf(float v) { return v > 0.f ? v : __expf(v) - 1.f; }

// compute one x-embed element: row rr (global), col
__device__ __forceinline__ float xembed(const float* __restrict__ centers,
                                        const float* __restrict__ Wt,
                                        const float* __restrict__ bt,
                                        int rr, int col) {
  const float* c = centers + rr * 12;
  float acc = bt[col];
  #pragma unroll
  for (int t = 0; t < 5; ++t) {
    float dx = c[(t+1)*2 + 0] - c[t*2 + 0];
    float dy = c[(t+1)*2 + 1] - c[t*2 + 1];
    acc += dx * Wt[(2 + 2*t)*HH + col] + dy * Wt[(3 + 2*t)*HH + col];
  }
  return acc;
}

// ================= prep: transposes + wpt + zero stats + x-embed ===============
struct PrepArgs {
  const float *centers, *W_traj, *b_traj;
  const float *n2e_W1, *n2e_W2, *e2n_W1, *e2n_W2, *W_fuse, *W_pred;
  float* ws;
  __hip_bfloat16 *w1te, *w2te, *w1tn, *w2tn, *wft, *wpt, *xg;
};

__global__ __launch_bounds__(256) void k_prep(PrepArgs a) {
  __shared__ float t[64][65];
  const int bid = blockIdx.x, tid = threadIdx.x;
  if (bid < 128) {
    const float* W; __hip_bfloat16* WT; int K, lb;
    if (bid < 32)      { W = a.n2e_W1; WT = a.w1te; K = 512; lb = bid; }
    else if (bid < 48) { W = a.n2e_W2; WT = a.w2te; K = 256; lb = bid - 32; }
    else if (bid < 80) { W = a.e2n_W1; WT = a.w1tn; K = 512; lb = bid - 48; }
    else if (bid < 96) { W = a.e2n_W2; WT = a.w2tn; K = 256; lb = bid - 80; }
    else               { W = a.W_fuse; WT = a.wft;  K = 512; lb = bid - 96; }
    int KB = K / 64;
    int k0 = (lb % KB) * 64, n0 = (lb / KB) * 64;
    int tx = tid & 63, ty = tid >> 6;
    #pragma unroll
    for (int i = 0; i < 16; ++i)
      t[ty + i*4][tx] = W[(size_t)(k0 + ty + i*4) * 256 + n0 + tx];
    __syncthreads();
    #pragma unroll
    for (int i = 0; i < 16; ++i)
      WT[(size_t)(n0 + ty + i*4) * K + k0 + tx] = __float2bfloat16(t[tx][ty + i*4]);
  } else if (bid < 192) {
    int idx = (bid - 128) * 256 + tid;
    int c = idx >> 8, k = idx & 255;
    a.wpt[idx] = __float2bfloat16(c < 60 ? a.W_pred[k * 60 + c] : 0.f);
  } else if (bid < 200) {
    a.ws[(bid - 192) * 256 + tid] = 0.f;
  } else {                          // x-embed: 16 rows per block (bid 200..263)
    int row0 = (bid - 200) * 16;
    #pragma unroll
    for (int r = 0; r < 16; ++r)
      a.xg[(size_t)(row0 + r)*256 + tid] =
          __float2bfloat16(xembed(a.centers, a.W_traj, a.b_traj, row0 + r, tid));
  }
}

// ---- XR/XS = xg @ W1_{top,bot}: single-wave pure GEMM, grid 512 ----
__global__ __launch_bounds__(64) void k_xrs2(
    const __hip_bfloat16* __restrict__ xg,    // 1024 x 256
    const __hip_bfloat16* __restrict__ W1T,   // 256 x 512 n-major
    const float* __restrict__ b1,
    __hip_bfloat16* __restrict__ xrs) {       // XR ++ XS
  const int lane = threadIdx.x;
  const int m16 = lane & 15, quad = lane >> 4;
  const int ko = quad * 8;
  const int rt = blockIdx.x >> 3, s = blockIdx.x & 7;
  const int half = s >> 2, j0 = (s & 3) * 64;
  const int row0 = rt * 16;
  __hip_bfloat16* dst = xrs + (size_t)half * 262144;

  f32x4 acc[4];
  #pragma unroll
  for (int jt = 0; jt < 4; ++jt) {
    float bv = half ? 0.f : b1[j0 + jt*16 + m16];
    acc[jt] = (f32x4){bv, bv, bv, bv};
  }
  #pragma unroll
  for (int ks = 0; ks < 8; ++ks) {
    short8 af = *reinterpret_cast<const short8*>(
        xg + (size_t)(row0 + m16)*256 + ks*32 + ko);
    short8 bf[4];
    #pragma unroll
    for (int jt = 0; jt < 4; ++jt)
      bf[jt] = *reinterpret_cast<const short8*>(
          W1T + (size_t)(j0 + jt*16 + m16)*512 + half*256 + ks*32 + ko);
    #pragma unroll
    for (int jt = 0; jt < 4; ++jt)
      acc[jt] = __builtin_amdgcn_mfma_f32_16x16x32_bf16(af, bf[jt], acc[jt], 0, 0, 0);
  }
  #pragma unroll
  for (int jt = 0; jt < 4; ++jt)
    #pragma unroll
    for (int r = 0; r < 4; ++r)
      dst[(size_t)(row0 + quad*4 + r)*256 + j0 + jt*16 + m16] =
          __float2bfloat16(acc[jt][r]);
}

// ================= edge MLP: factored L1 (global XR/XS reads), 36 KB LDS =======
__global__ __launch_bounds__(256, 4) void k_mlp6(
    const __hip_bfloat16* __restrict__ xrs,   // XR ++ XS
    const __hip_bfloat16* __restrict__ W2T,   // 256 x 256, n-major
    const float* __restrict__ b2,
    __hip_bfloat16* __restrict__ outp,        // e2
    float* __restrict__ stats) {
  __shared__ alignas(16) __hip_bfloat16 h1s[64][264];
  __shared__ float sst[2][256];
  __shared__ int sd64[64];
  __shared__ int rcf[64];
  const int tid = threadIdx.x;
  const int w = tid >> 6, lane = tid & 63;
  const int m16 = lane & 15, quad = lane >> 4;
  const int ko = quad * 8;
  const int blk = blockIdx.x;                 // 1008
  const int bb = blk / 63, lb = blk - bb*63;
  const int row0 = blk * 64;
  const int n0 = (lb * 64) / 63;              // receivers are n0, n0+1
  const int colw = w * 64;

  if (tid < 64) {
    int e = lb*64 + tid;
    int rc = e / 63; int jj = e - rc*63;
    sd64[tid] = jj + (jj >= rc ? 1 : 0);
    rcf[tid]  = rc - n0;                      // 0 or 1
  }
  sst[0][tid] = 0.f;
  sst[1][tid] = 0.f;
  __syncthreads();

  // ---- h1 = elu(XR[rc] + XS[sd]) -> h1s; operands direct from global (L2-hot) --
  {
    const int ty = tid >> 7;                  // rows ty*32 .. ty*32+31
    const int c2 = (tid & 127) * 2;
    const __hip_bfloat16* xrb = xrs + (size_t)(bb*64 + n0)*256 + c2;
    const __hip_bfloat16* xsb = xrs + 262144 + (size_t)bb*64*256 + c2;
    #pragma unroll 4
    for (int r2 = 0; r2 < 32; ++r2) {
      int r = ty*32 + r2;
      __hip_bfloat162 xa = *reinterpret_cast<const __hip_bfloat162*>(
          xrb + (size_t)rcf[r]*256);
      __hip_bfloat162 xs2 = *reinterpret_cast<const __hip_bfloat162*>(
          xsb + (size_t)sd64[r]*256);
      __hip_bfloat162 o;
      o.x = __float2bfloat16(eluf(__bfloat162float(xa.x) + __bfloat162float(xs2.x)));
      o.y = __float2bfloat16(eluf(__bfloat162float(xa.y) + __bfloat162float(xs2.y)));
      *reinterpret_cast<__hip_bfloat162*>(&h1s[r][c2]) = o;
    }
  }
  __syncthreads();

  // ---- layer 2: 64x256 @ 256x256, B direct from global (L2-hot 128 KB) ----
  f32x4 acc2[4][4];
  #pragma unroll
  for (int jt = 0; jt < 4; ++jt) {
    float bv = b2[colw + jt*16 + m16];
    #pragma unroll
    for (int mt = 0; mt < 4; ++mt) acc2[mt][jt] = (f32x4){bv, bv, bv, bv};
  }
  #pragma unroll
  for (int kt = 0; kt < 4; ++kt) {
    #pragma unroll
    for (int ks = 0; ks < 2; ++ks) {
      const int k0 = kt*64 + ks*32 + ko;
      short8 af[4], bf[4];
      #pragma unroll
      for (int jt = 0; jt < 4; ++jt)
        bf[jt] = *reinterpret_cast<const short8*>(
            W2T + (size_t)(colw + jt*16 + m16)*256 + k0);
      #pragma unroll
      for (int mt = 0; mt < 4; ++mt)
        af[mt] = *(const short8*)((const char*)h1s +
                     (size_t)(mt*16 + m16)*528 + k0*2);
      #pragma unroll
      for (int mt = 0; mt < 4; ++mt)
        #pragma unroll
        for (int jt = 0; jt < 4; ++jt)
          acc2[mt][jt] = __builtin_amdgcn_mfma_f32_16x16x32_bf16(af[mt], bf[jt],
                                                                 acc2[mt][jt], 0, 0, 0);
    }
  }
  __syncthreads();   // all h1 reads done before h1s is overwritten with h2

  // ---- ELU(h2) -> h1s; stats from registers ----
  #pragma unroll
  for (int jt = 0; jt < 4; ++jt) {
    float ps = 0.f, pq = 0.f;
    #pragma unroll
    for (int mt = 0; mt < 4; ++mt)
      #pragma unroll
      for (int r = 0; r < 4; ++r) {
        float hv = eluf(acc2[mt][jt][r]);
        h1s[mt*16 + quad*4 + r][colw + jt*16 + m16] = __float2bfloat16(hv);
        ps += hv; pq += hv * hv;
      }
    atomicAdd(&sst[0][colw + jt*16 + m16], ps);
    atomicAdd(&sst[1][colw + jt*16 + m16], pq);
  }
  __syncthreads();

  atomicAdd(&stats[tid], sst[0][tid]);
  atomicAdd(&stats[256 + tid], sst[1][tid]);
  #pragma unroll
  for (int i = 0; i < 8; ++i) {
    int u = i*256 + tid;
    int r = u >> 5, c = (u & 31) * 8;
    *reinterpret_cast<uint4*>(outp + (size_t)(row0 + r)*HH + c) =
        *reinterpret_cast<const uint4*>(&h1s[r][c]);
  }
}

// ---- BN-fused edge->node aggregation (proven): grid 2048 x 1024 ----
__global__ __launch_bounds__(1024) void k_agg2(const __hip_bfloat16* __restrict__ e2,
                                               const float* __restrict__ st,
                                               const float* __restrict__ gam,
                                               const float* __restrict__ bet,
                                               __hip_bfloat16* __restrict__ nodes) {
  __shared__ float red[32][256];
  const int blk = blockIdx.x;
  const int bn = blk >> 1, half = blk & 1;
  const int b = bn >> 6, n = bn & 63;
  const int tid = threadIdx.x;
  const int c8 = (tid & 31) * 8;
  const int rg = tid >> 5;
  const __hip_bfloat16* base = e2 + (size_t)b * EE * HH;
  float s[8] = {0.f,0.f,0.f,0.f,0.f,0.f,0.f,0.f};
  for (int j = rg; j < 63; j += 32) {
    const __hip_bfloat16* rp;
    if (half == 0) {
      rp = base + (size_t)(n*63 + j)*HH;
    } else {
      int i = j + (j >= n ? 1 : 0);
      int e = i*63 + n - (n > i ? 1 : 0);
      rp = base + (size_t)e*HH;
    }
    union { uint4 u; __hip_bfloat16 h[8]; } v;
    v.u = *reinterpret_cast<const uint4*>(rp + c8);
    #pragma unroll
    for (int jj = 0; jj < 8; ++jj) s[jj] += __bfloat162float(v.h[jj]);
  }
  #pragma unroll
  for (int jj = 0; jj < 8; jj += 4)
    *reinterpret_cast<float4*>(&red[rg][c8 + jj]) =
        (float4){s[jj], s[jj+1], s[jj+2], s[jj+3]};
  __syncthreads();
  if (tid < 256) {
    float S = 0.f;
    #pragma unroll
    for (int r = 0; r < 32; ++r) S += red[r][tid];
    const float inv = 1.f / (float)EROWS;
    float mean = st[tid] * inv;
    float var  = fmaxf(st[256 + tid] * inv - mean*mean, 0.f);
    float a = gam[tid] * rsqrtf(var + 1e-5f);
    float c0 = bet[tid] - mean * a;
    nodes[(size_t)bn*512 + half*256 + tid] = __float2bfloat16(a * S * (1.f/63.f) + c0);
  }
}

// ================= fused node MLP: single wave, grid 256 =======================
// Block = 16 rows x 64 out-cols. Layer 1 computed fully (redundant x4) into LDS,
// layer 2 for this block's out stripe. No barriers (single wave).
__global__ __launch_bounds__(64) void k_node(
    const __hip_bfloat16* __restrict__ nodes, // 1024 x 512
    const __hip_bfloat16* __restrict__ W1T,   // 256 x 512
    const float* __restrict__ b1,
    const __hip_bfloat16* __restrict__ W2T,   // 256 x 256
    const float* __restrict__ b2,
    __hip_bfloat16* __restrict__ m2,          // 1024 x 256
    float* __restrict__ stats) {
  __shared__ alignas(16) __hip_bfloat16 h1[16][264];
  __shared__ alignas(16) __hip_bfloat16 hl2[16][72];
  __shared__ float sst[2][64];
  const int lane = threadIdx.x;
  const int m16 = lane & 15, quad = lane >> 4;
  const int ko = quad * 8;
  const int rt = blockIdx.x >> 2;
  const int j2 = (blockIdx.x & 3) * 64;
  const int row0 = rt * 16;

  sst[0][lane] = 0.f;
  sst[1][lane] = 0.f;

  // layer 1: all 256 cols (16 j-tiles), K=512
  short8 af[16];
  #pragma unroll
  for (int ks = 0; ks < 16; ++ks)
    af[ks] = *reinterpret_cast<const short8*>(
        nodes + (size_t)(row0 + m16)*512 + ks*32 + ko);
  #pragma unroll
  for (int j1 = 0; j1 < 16; ++j1) {
    float bv = b1[j1*16 + m16];
    f32x4 acc = (f32x4){bv, bv, bv, bv};
    #pragma unroll
    for (int ks = 0; ks < 16; ++ks) {
      short8 bf = *reinterpret_cast<const short8*>(
          W1T + (size_t)(j1*16 + m16)*512 + ks*32 + ko);
      acc = __builtin_amdgcn_mfma_f32_16x16x32_bf16(af[ks], bf, acc, 0, 0, 0);
    }
    #pragma unroll
    for (int r = 0; r < 4; ++r)
      h1[quad*4 + r][j1*16 + m16] = __float2bfloat16(eluf(acc[r]));
  }

  // layer 2: out stripe j2..j2+63, K=256 (single wave: no barrier needed)
  f32x4 acc2[4];
  #pragma unroll
  for (int jt = 0; jt < 4; ++jt) {
    float bv = b2[j2 + jt*16 + m16];
    acc2[jt] = (f32x4){bv, bv, bv, bv};
  }
  #pragma unroll
  for (int ks = 0; ks < 8; ++ks) {
    short8 a2 = *(const short8*)((const char*)h1 + (size_t)m16*528 + (ks*32 + ko)*2);
    short8 bf[4];
    #pragma unroll
    for (int jt = 0; jt < 4; ++jt)
      bf[jt] = *reinterpret_cast<const short8*>(
          W2T + (size_t)(j2 + jt*16 + m16)*256 + ks*32 + ko);
    #pragma unroll
    for (int jt = 0; jt < 4; ++jt)
      acc2[jt] = __builtin_amdgcn_mfma_f32_16x16x32_bf16(a2, bf[jt], acc2[jt], 0, 0, 0);
  }
  #pragma unroll
  for (int jt = 0; jt < 4; ++jt) {
    float ps = 0.f, pq = 0.f;
    #pragma unroll
    for (int r = 0; r < 4; ++r) {
      float hv = eluf(acc2[jt][r]);
      hl2[quad*4 + r][jt*16 + m16] = __float2bfloat16(hv);
      ps += hv; pq += hv * hv;
    }
    atomicAdd(&sst[0][jt*16 + m16], ps);
    atomicAdd(&sst[1][jt*16 + m16], pq);
  }
  atomicAdd(&stats[j2 + lane], sst[0][lane]);
  atomicAdd(&stats[256 + j2 + lane], sst[1][lane]);
  #pragma unroll
  for (int i = 0; i < 2; ++i) {
    int u = i*64 + lane;
    int r = u >> 3, c = (u & 7) * 8;
    *reinterpret_cast<uint4*>(m2 + (size_t)(row0 + r)*256 + j2 + c) =
        *reinterpret_cast<const uint4*>(&hl2[r][c]);
  }
}

// ================= head fuse layer: single-wave, grid 256 ======================
__global__ __launch_bounds__(64) void k_hf(
    const __hip_bfloat16* __restrict__ xg,    // 1024 x 256
    const __hip_bfloat16* __restrict__ m2,    // 1024 x 256
    const float* __restrict__ stM,
    const float* __restrict__ gam,
    const float* __restrict__ bet,
    const __hip_bfloat16* __restrict__ WfT,   // 256 x 512
    const float* __restrict__ bfv,
    __hip_bfloat16* __restrict__ fg) {        // 1024 x 256
  __shared__ alignas(16) __hip_bfloat16 hls[16][72];
  __shared__ float bnA[256], bnC[256];
  const int lane = threadIdx.x;
  const int m16 = lane & 15, quad = lane >> 4;
  const int ko = quad * 8;
  const int row0 = (blockIdx.x >> 2) * 16;
  const int j0 = (blockIdx.x & 3) * 64;

  {
    const float inv = 1.f / (float)NROWS;
    #pragma unroll
    for (int j = 0; j < 4; ++j) {
      int k = lane*4 + j;
      float mean = stM[k] * inv;
      float var  = fmaxf(stM[256 + k] * inv - mean*mean, 0.f);
      float am = gam[k] * rsqrtf(var + 1e-5f);
      bnA[k] = am;
      bnC[k] = bet[k] - mean * am;
    }
  }

  f32x4 acc[4];
  #pragma unroll
  for (int jt = 0; jt < 4; ++jt) {
    float bv = bfv[j0 + jt*16 + m16];
    acc[jt] = (f32x4){bv, bv, bv, bv};
  }
  #pragma unroll
  for (int ks = 0; ks < 16; ++ks) {
    short8 af;
    if (ks < 8) {
      af = *reinterpret_cast<const short8*>(
          xg + (size_t)(row0 + m16)*256 + ks*32 + ko);
    } else {
      int k0 = (ks - 8)*32 + ko;
      union { uint4 u; __hip_bfloat16 h[8]; } v;
      v.u = *reinterpret_cast<const uint4*>(m2 + (size_t)(row0 + m16)*256 + k0);
      union { short8 s8; __hip_bfloat16 h[8]; } o;
      #pragma unroll
      for (int j = 0; j < 8; ++j)
        o.h[j] = __float2bfloat16(bnA[k0+j] * __bfloat162float(v.h[j]) + bnC[k0+j]);
      af = o.s8;
    }
    short8 bf[4];
    #pragma unroll
    for (int jt = 0; jt < 4; ++jt)
      bf[jt] = *reinterpret_cast<const short8*>(
          WfT + (size_t)(j0 + jt*16 + m16)*512 + ks*32 + ko);
    #pragma unroll
    for (int jt = 0; jt < 4; ++jt)
      acc[jt] = __builtin_amdgcn_mfma_f32_16x16x32_bf16(af, bf[jt], acc[jt], 0, 0, 0);
  }
  #pragma unroll
  for (int jt = 0; jt < 4; ++jt)
    #pragma unroll
    for (int r = 0; r < 4; ++r)
      hls[quad*4 + r][jt*16 + m16] = __float2bfloat16(acc[jt][r]);   // no activation
  #pragma unroll
  for (int i = 0; i < 2; ++i) {
    int u = i*64 + lane;
    int r = u >> 3, c = (u & 7) * 8;
    *reinterpret_cast<uint4*>(fg + (size_t)(row0 + r)*256 + j0 + c) =
        *reinterpret_cast<const uint4*>(&hls[r][c]);
  }
}

// ================= pred + cumsum: single-wave, grid 64 =========================
__global__ __launch_bounds__(64) void k_pred(
    const __hip_bfloat16* __restrict__ fg,    // 1024 x 256
    const __hip_bfloat16* __restrict__ WpT,   // 64 x 256 (zero-padded)
    const float* __restrict__ bp,
    const float* __restrict__ centers,
    float* __restrict__ out) {
  __shared__ float rl[16][68];
  const int lane = threadIdx.x;
  const int m16 = lane & 15, quad = lane >> 4;
  const int ko = quad * 8;
  const int row0 = blockIdx.x * 16;

  f32x4 acc[4];
  #pragma unroll
  for (int jt = 0; jt < 4; ++jt) {
    int c = jt*16 + m16;
    float bv = (c < 60) ? bp[c] : 0.f;
    acc[jt] = (f32x4){bv, bv, bv, bv};
  }
  #pragma unroll
  for (int ks = 0; ks < 8; ++ks) {
    short8 af = *reinterpret_cast<const short8*>(
        fg + (size_t)(row0 + m16)*256 + ks*32 + ko);
    short8 bf[4];
    #pragma unroll
    for (int jt = 0; jt < 4; ++jt)
      bf[jt] = *reinterpret_cast<const short8*>(
          WpT + (size_t)(jt*16 + m16)*256 + ks*32 + ko);
    #pragma unroll
    for (int jt = 0; jt < 4; ++jt)
      acc[jt] = __builtin_amdgcn_mfma_f32_16x16x32_bf16(af, bf[jt], acc[jt], 0, 0, 0);
  }
  #pragma unroll
  for (int jt = 0; jt < 4; ++jt) {
    int c = jt*16 + m16;
    #pragma unroll
    for (int r = 0; r < 4; ++r) {
      int lr = quad*4 + r;
      rl[lr][c] = acc[jt][r];
      if (c < 60) out[(size_t)(row0 + lr)*60 + c] = acc[jt][r];
    }
  }
  if (lane < 32) {
    int lr = lane >> 1, xy = lane & 1;
    int grow = row0 + lr;
    float run = centers[(size_t)(grow*PREVN + 5)*2 + xy];
    #pragma unroll
    for (int p = 0; p < PREDN; ++p) {
      run += rl[lr][2*p + xy];
      out[61440 + (size_t)grow*60 + 2*p + xy] = run;
    }
  }
}

extern "C" void kernel_launch(void* const* d_in, const int* in_sizes, int n_in,
                              void* d_out, int out_size, void* d_ws, size_t ws_size,
                              hipStream_t stream) {
  const float* centers = (const float*)d_in[0];
  float* ws = (float*)d_ws;
  __hip_bfloat16* wb = (__hip_bfloat16*)(ws + F32_END);
  __hip_bfloat16* xrs = (__hip_bfloat16*)(ws + OFF_XRS);

  const float* W_traj = (const float*)d_in[3];
  const float* b_traj = (const float*)d_in[4];
  const float* n2e_b1 = (const float*)d_in[6];
  const float* n2e_b2 = (const float*)d_in[8];
  const float* n2e_g  = (const float*)d_in[9];
  const float* n2e_be = (const float*)d_in[10];
  const float* e2n_b1 = (const float*)d_in[12];
  const float* e2n_b2 = (const float*)d_in[14];
  const float* e2n_g  = (const float*)d_in[15];
  const float* e2n_be = (const float*)d_in[16];
  const float* b_fuse = (const float*)d_in[18];
  const float* b_pred = (const float*)d_in[20];

  PrepArgs pa;
  pa.centers = centers; pa.W_traj = W_traj; pa.b_traj = b_traj;
  pa.n2e_W1 = (const float*)d_in[5];  pa.n2e_W2 = (const float*)d_in[7];
  pa.e2n_W1 = (const float*)d_in[11]; pa.e2n_W2 = (const float*)d_in[13];
  pa.W_fuse = (const float*)d_in[17]; pa.W_pred = (const float*)d_in[19];
  pa.ws = ws;
  pa.w1te = wb + BO_W1TE; pa.w2te = wb + BO_W2TE;
  pa.w1tn = wb + BO_W1TN; pa.w2tn = wb + BO_W2TN;
  pa.wft = wb + BO_WFT;   pa.wpt = wb + BO_WPT;
  pa.xg = wb + BO_XG;

  k_prep<<<264, 256, 0, stream>>>(pa);
  k_xrs2<<<512, 64, 0, stream>>>(wb + BO_XG, wb + BO_W1TE, n2e_b1, xrs);
  k_mlp6<<<EROWS/64, 256, 0, stream>>>(xrs, wb + BO_W2TE, n2e_b2, wb + BO_E2,
                                       ws + OFF_STATS_E);
  k_agg2<<<2*NROWS, 1024, 0, stream>>>(wb + BO_E2, ws + OFF_STATS_E, n2e_g, n2e_be,
                                       wb + BO_NODES);
  k_node<<<256, 64, 0, stream>>>(wb + BO_NODES, wb + BO_W1TN, e2n_b1,
                                 wb + BO_W2TN, e2n_b2, wb + BO_M2,
                                 ws + OFF_STATS_M);
  k_hf<<<256, 64, 0, stream>>>(wb + BO_XG, wb + BO_M2, ws + OFF_STATS_M,
                               e2n_g, e2n_be, wb + BO_WFT, b_fuse, wb + BO_FG);
  k_pred<<<64, 64, 0, stream>>>(wb + BO_FG, wb + BO_WPT, b_pred, centers,
                                (float*)d_out);
}

// Round 17
// 199.823 us; speedup vs baseline: 1.2355x; 1.2355x over previous
//
#include <hip/hip_runtime.h>
#include <hip/hip_bf16.h>

#define BB 16
#define NN 64
#define PREVN 6
#define PREDN 30
#define HH 256
#define EE 4032              // NN*(NN-1)
#define EROWS (BB*EE)        // 64512
#define NROWS (BB*NN)        // 1024

typedef short short8 __attribute__((ext_vector_type(8)));
typedef float f32x4 __attribute__((ext_vector_type(4)));

// ---- f32 workspace layout (float element offsets) ----
enum : int {
  OFF_STATS_E = 0,       // 1024: [0:256]=sum [256:512]=sumsq
  OFF_STATS_M = 1024,    // 1024
  OFF_XRS     = 2048,    // 262144 f32 slots = 524288 bf16: XR ++ XS
  F32_END     = 264192
};
// ---- bf16 area (element offsets within wb = (bf16*)(ws + F32_END)) ----
enum : size_t {
  BO_W1TE  = 0,          // 256*512 (n2e W1^T)
  BO_W2TE  = 131072,     // 256*256
  BO_W1TN  = 196608,     // 256*512 (e2n W1^T)
  BO_W2TN  = 327680,     // 256*256
  BO_WFT   = 393216,     // 256*512 (W_fuse^T)
  BO_WPT   = 524288,     // 64*256  (W_pred^T, zero-padded cols 60..63)
  BO_XG    = 540672,     // 1024*256 raw x (bf16)
  BO_NODES = 802816,     // 1024*512
  BO_H1G   = 1327104,    // 1024*256 node-MLP h1
  BO_M2    = 1589248,    // 1024*256
  BO_FG    = 1851392,    // 1024*256 fused
  BO_E2    = 2113536     // 64512*256
};

// fast ELU: exp(x)-1 via v_exp_f32
__device__ __forceinline__ float eluf(float v) { return v > 0.f ? v : __expf(v) - 1.f; }

// compute one x-embed element: row rr (global), col
__device__ __forceinline__ float xembed(const float* __restrict__ centers,
                                        const float* __restrict__ Wt,
                                        const float* __restrict__ bt,
                                        int rr, int col) {
  const float* c = centers + rr * 12;
  float acc = bt[col];
  #pragma unroll
  for (int t = 0; t < 5; ++t) {
    float dx = c[(t+1)*2 + 0] - c[t*2 + 0];
    float dy = c[(t+1)*2 + 1] - c[t*2 + 1];
    acc += dx * Wt[(2 + 2*t)*HH + col] + dy * Wt[(3 + 2*t)*HH + col];
  }
  return acc;
}

// ================= prep: transposes + wpt + zero stats + x-embed ===============
struct PrepArgs {
  const float *centers, *W_traj, *b_traj;
  const float *n2e_W1, *n2e_W2, *e2n_W1, *e2n_W2, *W_fuse, *W_pred;
  float* ws;
  __hip_bfloat16 *w1te, *w2te, *w1tn, *w2tn, *wft, *wpt, *xg;
};

__global__ __launch_bounds__(256) void k_prep(PrepArgs a) {
  __shared__ float t[64][65];
  const int bid = blockIdx.x, tid = threadIdx.x;
  if (bid < 128) {
    const float* W; __hip_bfloat16* WT; int K, lb;
    if (bid < 32)      { W = a.n2e_W1; WT = a.w1te; K = 512; lb = bid; }
    else if (bid < 48) { W = a.n2e_W2; WT = a.w2te; K = 256; lb = bid - 32; }
    else if (bid < 80) { W = a.e2n_W1; WT = a.w1tn; K = 512; lb = bid - 48; }
    else if (bid < 96) { W = a.e2n_W2; WT = a.w2tn; K = 256; lb = bid - 80; }
    else               { W = a.W_fuse; WT = a.wft;  K = 512; lb = bid - 96; }
    int KB = K / 64;
    int k0 = (lb % KB) * 64, n0 = (lb / KB) * 64;
    int tx = tid & 63, ty = tid >> 6;
    #pragma unroll
    for (int i = 0; i < 16; ++i)
      t[ty + i*4][tx] = W[(size_t)(k0 + ty + i*4) * 256 + n0 + tx];
    __syncthreads();
    #pragma unroll
    for (int i = 0; i < 16; ++i)
      WT[(size_t)(n0 + ty + i*4) * K + k0 + tx] = __float2bfloat16(t[tx][ty + i*4]);
  } else if (bid < 192) {
    int idx = (bid - 128) * 256 + tid;
    int c = idx >> 8, k = idx & 255;
    a.wpt[idx] = __float2bfloat16(c < 60 ? a.W_pred[k * 60 + c] : 0.f);
  } else if (bid < 200) {
    a.ws[(bid - 192) * 256 + tid] = 0.f;
  } else {                          // x-embed: 16 rows per block (bid 200..263)
    int row0 = (bid - 200) * 16;
    #pragma unroll
    for (int r = 0; r < 16; ++r)
      a.xg[(size_t)(row0 + r)*256 + tid] =
          __float2bfloat16(xembed(a.centers, a.W_traj, a.b_traj, row0 + r, tid));
  }
}

// ---- XR/XS = xg @ W1_{top,bot}: single-wave pure GEMM, grid 512 ----
__global__ __launch_bounds__(64) void k_xrs2(
    const __hip_bfloat16* __restrict__ xg,    // 1024 x 256
    const __hip_bfloat16* __restrict__ W1T,   // 256 x 512 n-major
    const float* __restrict__ b1,
    __hip_bfloat16* __restrict__ xrs) {       // XR ++ XS
  const int lane = threadIdx.x;
  const int m16 = lane & 15, quad = lane >> 4;
  const int ko = quad * 8;
  const int rt = blockIdx.x >> 3, s = blockIdx.x & 7;
  const int half = s >> 2, j0 = (s & 3) * 64;
  const int row0 = rt * 16;
  __hip_bfloat16* dst = xrs + (size_t)half * 262144;

  f32x4 acc[4];
  #pragma unroll
  for (int jt = 0; jt < 4; ++jt) {
    float bv = half ? 0.f : b1[j0 + jt*16 + m16];
    acc[jt] = (f32x4){bv, bv, bv, bv};
  }
  #pragma unroll
  for (int ks = 0; ks < 8; ++ks) {
    short8 af = *reinterpret_cast<const short8*>(
        xg + (size_t)(row0 + m16)*256 + ks*32 + ko);
    short8 bf[4];
    #pragma unroll
    for (int jt = 0; jt < 4; ++jt)
      bf[jt] = *reinterpret_cast<const short8*>(
          W1T + (size_t)(j0 + jt*16 + m16)*512 + half*256 + ks*32 + ko);
    #pragma unroll
    for (int jt = 0; jt < 4; ++jt)
      acc[jt] = __builtin_amdgcn_mfma_f32_16x16x32_bf16(af, bf[jt], acc[jt], 0, 0, 0);
  }
  #pragma unroll
  for (int jt = 0; jt < 4; ++jt)
    #pragma unroll
    for (int r = 0; r < 4; ++r)
      dst[(size_t)(row0 + quad*4 + r)*256 + j0 + jt*16 + m16] =
          __float2bfloat16(acc[jt][r]);
}

// ================= edge MLP: factored L1 (global XR/XS reads), 36 KB LDS =======
__global__ __launch_bounds__(256, 4) void k_mlp6(
    const __hip_bfloat16* __restrict__ xrs,   // XR ++ XS
    const __hip_bfloat16* __restrict__ W2T,   // 256 x 256, n-major
    const float* __restrict__ b2,
    __hip_bfloat16* __restrict__ outp,        // e2
    float* __restrict__ stats) {
  __shared__ alignas(16) __hip_bfloat16 h1s[64][264];
  __shared__ float sst[2][256];
  __shared__ int sd64[64];
  __shared__ int rcf[64];
  const int tid = threadIdx.x;
  const int w = tid >> 6, lane = tid & 63;
  const int m16 = lane & 15, quad = lane >> 4;
  const int ko = quad * 8;
  const int blk = blockIdx.x;                 // 1008
  const int bb = blk / 63, lb = blk - bb*63;
  const int row0 = blk * 64;
  const int n0 = (lb * 64) / 63;              // receivers are n0, n0+1
  const int colw = w * 64;

  if (tid < 64) {
    int e = lb*64 + tid;
    int rc = e / 63; int jj = e - rc*63;
    sd64[tid] = jj + (jj >= rc ? 1 : 0);
    rcf[tid]  = rc - n0;                      // 0 or 1
  }
  sst[0][tid] = 0.f;
  sst[1][tid] = 0.f;
  __syncthreads();

  // ---- h1 = elu(XR[rc] + XS[sd]) -> h1s; operands direct from global (L2-hot) --
  {
    const int ty = tid >> 7;                  // rows ty*32 .. ty*32+31
    const int c2 = (tid & 127) * 2;
    const __hip_bfloat16* xrb = xrs + (size_t)(bb*64 + n0)*256 + c2;
    const __hip_bfloat16* xsb = xrs + 262144 + (size_t)bb*64*256 + c2;
    #pragma unroll 4
    for (int r2 = 0; r2 < 32; ++r2) {
      int r = ty*32 + r2;
      __hip_bfloat162 xa = *reinterpret_cast<const __hip_bfloat162*>(
          xrb + (size_t)rcf[r]*256);
      __hip_bfloat162 xs2 = *reinterpret_cast<const __hip_bfloat162*>(
          xsb + (size_t)sd64[r]*256);
      __hip_bfloat162 o;
      o.x = __float2bfloat16(eluf(__bfloat162float(xa.x) + __bfloat162float(xs2.x)));
      o.y = __float2bfloat16(eluf(__bfloat162float(xa.y) + __bfloat162float(xs2.y)));
      *reinterpret_cast<__hip_bfloat162*>(&h1s[r][c2]) = o;
    }
  }
  __syncthreads();

  // ---- layer 2: 64x256 @ 256x256, B direct from global (L2-hot 128 KB) ----
  f32x4 acc2[4][4];
  #pragma unroll
  for (int jt = 0; jt < 4; ++jt) {
    float bv = b2[colw + jt*16 + m16];
    #pragma unroll
    for (int mt = 0; mt < 4; ++mt) acc2[mt][jt] = (f32x4){bv, bv, bv, bv};
  }
  #pragma unroll
  for (int kt = 0; kt < 4; ++kt) {
    #pragma unroll
    for (int ks = 0; ks < 2; ++ks) {
      const int k0 = kt*64 + ks*32 + ko;
      short8 af[4], bf[4];
      #pragma unroll
      for (int jt = 0; jt < 4; ++jt)
        bf[jt] = *reinterpret_cast<const short8*>(
            W2T + (size_t)(colw + jt*16 + m16)*256 + k0);
      #pragma unroll
      for (int mt = 0; mt < 4; ++mt)
        af[mt] = *(const short8*)((const char*)h1s +
                     (size_t)(mt*16 + m16)*528 + k0*2);
      #pragma unroll
      for (int mt = 0; mt < 4; ++mt)
        #pragma unroll
        for (int jt = 0; jt < 4; ++jt)
          acc2[mt][jt] = __builtin_amdgcn_mfma_f32_16x16x32_bf16(af[mt], bf[jt],
                                                                 acc2[mt][jt], 0, 0, 0);
    }
  }
  __syncthreads();   // all h1 reads done before h1s is overwritten with h2

  // ---- ELU(h2) -> h1s; stats from registers ----
  #pragma unroll
  for (int jt = 0; jt < 4; ++jt) {
    float ps = 0.f, pq = 0.f;
    #pragma unroll
    for (int mt = 0; mt < 4; ++mt)
      #pragma unroll
      for (int r = 0; r < 4; ++r) {
        float hv = eluf(acc2[mt][jt][r]);
        h1s[mt*16 + quad*4 + r][colw + jt*16 + m16] = __float2bfloat16(hv);
        ps += hv; pq += hv * hv;
      }
    atomicAdd(&sst[0][colw + jt*16 + m16], ps);
    atomicAdd(&sst[1][colw + jt*16 + m16], pq);
  }
  __syncthreads();

  atomicAdd(&stats[tid], sst[0][tid]);
  atomicAdd(&stats[256 + tid], sst[1][tid]);
  #pragma unroll
  for (int i = 0; i < 8; ++i) {
    int u = i*256 + tid;
    int r = u >> 5, c = (u & 31) * 8;
    *reinterpret_cast<uint4*>(outp + (size_t)(row0 + r)*HH + c) =
        *reinterpret_cast<const uint4*>(&h1s[r][c]);
  }
}

// ---- BN-fused edge->node aggregation (proven): grid 2048 x 1024 ----
__global__ __launch_bounds__(1024) void k_agg2(const __hip_bfloat16* __restrict__ e2,
                                               const float* __restrict__ st,
                                               const float* __restrict__ gam,
                                               const float* __restrict__ bet,
                                               __hip_bfloat16* __restrict__ nodes) {
  __shared__ float red[32][256];
  const int blk = blockIdx.x;
  const int bn = blk >> 1, half = blk & 1;
  const int b = bn >> 6, n = bn & 63;
  const int tid = threadIdx.x;
  const int c8 = (tid & 31) * 8;
  const int rg = tid >> 5;
  const __hip_bfloat16* base = e2 + (size_t)b * EE * HH;
  float s[8] = {0.f,0.f,0.f,0.f,0.f,0.f,0.f,0.f};
  for (int j = rg; j < 63; j += 32) {
    const __hip_bfloat16* rp;
    if (half == 0) {
      rp = base + (size_t)(n*63 + j)*HH;
    } else {
      int i = j + (j >= n ? 1 : 0);
      int e = i*63 + n - (n > i ? 1 : 0);
      rp = base + (size_t)e*HH;
    }
    union { uint4 u; __hip_bfloat16 h[8]; } v;
    v.u = *reinterpret_cast<const uint4*>(rp + c8);
    #pragma unroll
    for (int jj = 0; jj < 8; ++jj) s[jj] += __bfloat162float(v.h[jj]);
  }
  #pragma unroll
  for (int jj = 0; jj < 8; jj += 4)
    *reinterpret_cast<float4*>(&red[rg][c8 + jj]) =
        (float4){s[jj], s[jj+1], s[jj+2], s[jj+3]};
  __syncthreads();
  if (tid < 256) {
    float S = 0.f;
    #pragma unroll
    for (int r = 0; r < 32; ++r) S += red[r][tid];
    const float inv = 1.f / (float)EROWS;
    float mean = st[tid] * inv;
    float var  = fmaxf(st[256 + tid] * inv - mean*mean, 0.f);
    float a = gam[tid] * rsqrtf(var + 1e-5f);
    float c0 = bet[tid] - mean * a;
    nodes[(size_t)bn*512 + half*256 + tid] = __float2bfloat16(a * S * (1.f/63.f) + c0);
  }
}

// ================= node MLP layer 1: single-wave, grid 512 (32-col stripes) ====
__global__ __launch_bounds__(64) void k_n1(
    const __hip_bfloat16* __restrict__ nodes, // 1024 x 512
    const __hip_bfloat16* __restrict__ W1T,   // 256 x 512
    const float* __restrict__ b1,
    __hip_bfloat16* __restrict__ h1g) {       // 1024 x 256
  __shared__ alignas(16) __hip_bfloat16 hls[16][40];
  const int lane = threadIdx.x;
  const int m16 = lane & 15, quad = lane >> 4;
  const int ko = quad * 8;
  const int row0 = (blockIdx.x >> 3) * 16;
  const int j0 = (blockIdx.x & 7) * 32;

  f32x4 acc[2];
  #pragma unroll
  for (int jt = 0; jt < 2; ++jt) {
    float bv = b1[j0 + jt*16 + m16];
    acc[jt] = (f32x4){bv, bv, bv, bv};
  }
  #pragma unroll
  for (int ks = 0; ks < 16; ++ks) {
    short8 af = *reinterpret_cast<const short8*>(
        nodes + (size_t)(row0 + m16)*512 + ks*32 + ko);
    short8 bf[2];
    #pragma unroll
    for (int jt = 0; jt < 2; ++jt)
      bf[jt] = *reinterpret_cast<const short8*>(
          W1T + (size_t)(j0 + jt*16 + m16)*512 + ks*32 + ko);
    #pragma unroll
    for (int jt = 0; jt < 2; ++jt)
      acc[jt] = __builtin_amdgcn_mfma_f32_16x16x32_bf16(af, bf[jt], acc[jt], 0, 0, 0);
  }
  #pragma unroll
  for (int jt = 0; jt < 2; ++jt)
    #pragma unroll
    for (int r = 0; r < 4; ++r)
      hls[quad*4 + r][jt*16 + m16] = __float2bfloat16(eluf(acc[jt][r]));
  // single wave: compiler lgkmcnt covers LDS RAW
  {
    int r = lane >> 2, c = (lane & 3) * 8;
    *reinterpret_cast<uint4*>(h1g + (size_t)(row0 + r)*256 + j0 + c) =
        *reinterpret_cast<const uint4*>(&hls[r][c]);
  }
}

// ================= node MLP layer 2 + stats: single-wave, grid 512 =============
__global__ __launch_bounds__(64) void k_n2(
    const __hip_bfloat16* __restrict__ h1g,   // 1024 x 256
    const __hip_bfloat16* __restrict__ W2T,   // 256 x 256
    const float* __restrict__ b2,
    __hip_bfloat16* __restrict__ m2,          // 1024 x 256
    float* __restrict__ stats) {
  __shared__ alignas(16) __hip_bfloat16 hls[16][40];
  __shared__ float sst[2][32];
  const int lane = threadIdx.x;
  const int m16 = lane & 15, quad = lane >> 4;
  const int ko = quad * 8;
  const int row0 = (blockIdx.x >> 3) * 16;
  const int j0 = (blockIdx.x & 7) * 32;

  if (lane < 32) { sst[0][lane] = 0.f; sst[1][lane] = 0.f; }

  f32x4 acc[2];
  #pragma unroll
  for (int jt = 0; jt < 2; ++jt) {
    float bv = b2[j0 + jt*16 + m16];
    acc[jt] = (f32x4){bv, bv, bv, bv};
  }
  #pragma unroll
  for (int ks = 0; ks < 8; ++ks) {
    short8 af = *reinterpret_cast<const short8*>(
        h1g + (size_t)(row0 + m16)*256 + ks*32 + ko);
    short8 bf[2];
    #pragma unroll
    for (int jt = 0; jt < 2; ++jt)
      bf[jt] = *reinterpret_cast<const short8*>(
          W2T + (size_t)(j0 + jt*16 + m16)*256 + ks*32 + ko);
    #pragma unroll
    for (int jt = 0; jt < 2; ++jt)
      acc[jt] = __builtin_amdgcn_mfma_f32_16x16x32_bf16(af, bf[jt], acc[jt], 0, 0, 0);
  }
  #pragma unroll
  for (int jt = 0; jt < 2; ++jt) {
    float ps = 0.f, pq = 0.f;
    #pragma unroll
    for (int r = 0; r < 4; ++r) {
      float hv = eluf(acc[jt][r]);
      hls[quad*4 + r][jt*16 + m16] = __float2bfloat16(hv);
      ps += hv; pq += hv * hv;
    }
    atomicAdd(&sst[0][jt*16 + m16], ps);
    atomicAdd(&sst[1][jt*16 + m16], pq);
  }
  if (lane < 32) {
    atomicAdd(&stats[j0 + lane], sst[0][lane]);
    atomicAdd(&stats[256 + j0 + lane], sst[1][lane]);
  }
  {
    int r = lane >> 2, c = (lane & 3) * 8;
    *reinterpret_cast<uint4*>(m2 + (size_t)(row0 + r)*256 + j0 + c) =
        *reinterpret_cast<const uint4*>(&hls[r][c]);
  }
}

// ================= head fuse layer: single-wave, grid 512 ======================
__global__ __launch_bounds__(64) void k_hf(
    const __hip_bfloat16* __restrict__ xg,    // 1024 x 256
    const __hip_bfloat16* __restrict__ m2,    // 1024 x 256
    const float* __restrict__ stM,
    const float* __restrict__ gam,
    const float* __restrict__ bet,
    const __hip_bfloat16* __restrict__ WfT,   // 256 x 512
    const float* __restrict__ bfv,
    __hip_bfloat16* __restrict__ fg) {        // 1024 x 256
  __shared__ alignas(16) __hip_bfloat16 hls[16][40];
  __shared__ float bnA[256], bnC[256];
  const int lane = threadIdx.x;
  const int m16 = lane & 15, quad = lane >> 4;
  const int ko = quad * 8;
  const int row0 = (blockIdx.x >> 3) * 16;
  const int j0 = (blockIdx.x & 7) * 32;

  {
    const float inv = 1.f / (float)NROWS;
    #pragma unroll
    for (int j = 0; j < 4; ++j) {
      int k = lane*4 + j;
      float mean = stM[k] * inv;
      float var  = fmaxf(stM[256 + k] * inv - mean*mean, 0.f);
      float am = gam[k] * rsqrtf(var + 1e-5f);
      bnA[k] = am;
      bnC[k] = bet[k] - mean * am;
    }
  }

  f32x4 acc[2];
  #pragma unroll
  for (int jt = 0; jt < 2; ++jt) {
    float bv = bfv[j0 + jt*16 + m16];
    acc[jt] = (f32x4){bv, bv, bv, bv};
  }
  #pragma unroll
  for (int ks = 0; ks < 16; ++ks) {
    short8 af;
    if (ks < 8) {
      af = *reinterpret_cast<const short8*>(
          xg + (size_t)(row0 + m16)*256 + ks*32 + ko);
    } else {
      int k0 = (ks - 8)*32 + ko;
      union { uint4 u; __hip_bfloat16 h[8]; } v;
      v.u = *reinterpret_cast<const uint4*>(m2 + (size_t)(row0 + m16)*256 + k0);
      union { short8 s8; __hip_bfloat16 h[8]; } o;
      #pragma unroll
      for (int j = 0; j < 8; ++j)
        o.h[j] = __float2bfloat16(bnA[k0+j] * __bfloat162float(v.h[j]) + bnC[k0+j]);
      af = o.s8;
    }
    short8 bf[2];
    #pragma unroll
    for (int jt = 0; jt < 2; ++jt)
      bf[jt] = *reinterpret_cast<const short8*>(
          WfT + (size_t)(j0 + jt*16 + m16)*512 + ks*32 + ko);
    #pragma unroll
    for (int jt = 0; jt < 2; ++jt)
      acc[jt] = __builtin_amdgcn_mfma_f32_16x16x32_bf16(af, bf[jt], acc[jt], 0, 0, 0);
  }
  #pragma unroll
  for (int jt = 0; jt < 2; ++jt)
    #pragma unroll
    for (int r = 0; r < 4; ++r)
      hls[quad*4 + r][jt*16 + m16] = __float2bfloat16(acc[jt][r]);   // no activation
  {
    int r = lane >> 2, c = (lane & 3) * 8;
    *reinterpret_cast<uint4*>(fg + (size_t)(row0 + r)*256 + j0 + c) =
        *reinterpret_cast<const uint4*>(&hls[r][c]);
  }
}

// ================= pred + cumsum: single-wave, grid 64 =========================
__global__ __launch_bounds__(64) void k_pred(
    const __hip_bfloat16* __restrict__ fg,    // 1024 x 256
    const __hip_bfloat16* __restrict__ WpT,   // 64 x 256 (zero-padded)
    const float* __restrict__ bp,
    const float* __restrict__ centers,
    float* __restrict__ out) {
  __shared__ float rl[16][68];
  const int lane = threadIdx.x;
  const int m16 = lane & 15, quad = lane >> 4;
  const int ko = quad * 8;
  const int row0 = blockIdx.x * 16;

  f32x4 acc[4];
  #pragma unroll
  for (int jt = 0; jt < 4; ++jt) {
    int c = jt*16 + m16;
    float bv = (c < 60) ? bp[c] : 0.f;
    acc[jt] = (f32x4){bv, bv, bv, bv};
  }
  #pragma unroll
  for (int ks = 0; ks < 8; ++ks) {
    short8 af = *reinterpret_cast<const short8*>(
        fg + (size_t)(row0 + m16)*256 + ks*32 + ko);
    short8 bf[4];
    #pragma unroll
    for (int jt = 0; jt < 4; ++jt)
      bf[jt] = *reinterpret_cast<const short8*>(
          WpT + (size_t)(jt*16 + m16)*256 + ks*32 + ko);
    #pragma unroll
    for (int jt = 0; jt < 4; ++jt)
      acc[jt] = __builtin_amdgcn_mfma_f32_16x16x32_bf16(af, bf[jt], acc[jt], 0, 0, 0);
  }
  #pragma unroll
  for (int jt = 0; jt < 4; ++jt) {
    int c = jt*16 + m16;
    #pragma unroll
    for (int r = 0; r < 4; ++r) {
      int lr = quad*4 + r;
      rl[lr][c] = acc[jt][r];
      if (c < 60) out[(size_t)(row0 + lr)*60 + c] = acc[jt][r];
    }
  }
  if (lane < 32) {
    int lr = lane >> 1, xy = lane & 1;
    int grow = row0 + lr;
    float run = centers[(size_t)(grow*PREVN + 5)*2 + xy];
    #pragma unroll
    for (int p = 0; p < PREDN; ++p) {
      run += rl[lr][2*p + xy];
      out[61440 + (size_t)grow*60 + 2*p + xy] = run;
    }
  }
}

extern "C" void kernel_launch(void* const* d_in, const int* in_sizes, int n_in,
                              void* d_out, int out_size, void* d_ws, size_t ws_size,
                              hipStream_t stream) {
  const float* centers = (const float*)d_in[0];
  float* ws = (float*)d_ws;
  __hip_bfloat16* wb = (__hip_bfloat16*)(ws + F32_END);
  __hip_bfloat16* xrs = (__hip_bfloat16*)(ws + OFF_XRS);

  const float* W_traj = (const float*)d_in[3];
  const float* b_traj = (const float*)d_in[4];
  const float* n2e_b1 = (const float*)d_in[6];
  const float* n2e_b2 = (const float*)d_in[8];
  const float* n2e_g  = (const float*)d_in[9];
  const float* n2e_be = (const float*)d_in[10];
  const float* e2n_b1 = (const float*)d_in[12];
  const float* e2n_b2 = (const float*)d_in[14];
  const float* e2n_g  = (const float*)d_in[15];
  const float* e2n_be = (const float*)d_in[16];
  const float* b_fuse = (const float*)d_in[18];
  const float* b_pred = (const float*)d_in[20];

  PrepArgs pa;
  pa.centers = centers; pa.W_traj = W_traj; pa.b_traj = b_traj;
  pa.n2e_W1 = (const float*)d_in[5];  pa.n2e_W2 = (const float*)d_in[7];
  pa.e2n_W1 = (const float*)d_in[11]; pa.e2n_W2 = (const float*)d_in[13];
  pa.W_fuse = (const float*)d_in[17]; pa.W_pred = (const float*)d_in[19];
  pa.ws = ws;
  pa.w1te = wb + BO_W1TE; pa.w2te = wb + BO_W2TE;
  pa.w1tn = wb + BO_W1TN; pa.w2tn = wb + BO_W2TN;
  pa.wft = wb + BO_WFT;   pa.wpt = wb + BO_WPT;
  pa.xg = wb + BO_XG;

  k_prep<<<264, 256, 0, stream>>>(pa);
  k_xrs2<<<512, 64, 0, stream>>>(wb + BO_XG, wb + BO_W1TE, n2e_b1, xrs);
  k_mlp6<<<EROWS/64, 256, 0, stream>>>(xrs, wb + BO_W2TE, n2e_b2, wb + BO_E2,
                                       ws + OFF_STATS_E);
  k_agg2<<<2*NROWS, 1024, 0, stream>>>(wb + BO_E2, ws + OFF_STATS_E, n2e_g, n2e_be,
                                       wb + BO_NODES);
  k_n1<<<512, 64, 0, stream>>>(wb + BO_NODES, wb + BO_W1TN, e2n_b1, wb + BO_H1G);
  k_n2<<<512, 64, 0, stream>>>(wb + BO_H1G, wb + BO_W2TN, e2n_b2, wb + BO_M2,
                               ws + OFF_STATS_M);
  k_hf<<<512, 64, 0, stream>>>(wb + BO_XG, wb + BO_M2, ws + OFF_STATS_M,
                               e2n_g, e2n_be, wb + BO_WFT, b_fuse, wb + BO_FG);
  k_pred<<<64, 64, 0, stream>>>(wb + BO_FG, wb + BO_WPT, b_pred, centers,
                                (float*)d_out);
}